// Round 2
// baseline (695.296 us; speedup 1.0000x reference)
//
#include <hip/hip_runtime.h>
#include <hip/hip_bf16.h>

typedef __bf16 bf16;
typedef bf16 bf16x8 __attribute__((ext_vector_type(8)));
typedef float f32x4 __attribute__((ext_vector_type(4)));

#define MFMA16(a, b, c) __builtin_amdgcn_mfma_f32_16x16x32_bf16((a), (b), (c), 0, 0, 0)
#define UNROLL _Pragma("unroll")

__device__ __forceinline__ float fast_rcp(float x) { return __builtin_amdgcn_rcpf(x); }
__device__ __forceinline__ float fast_rsq(float x) { return __builtin_amdgcn_rsqf(x); }
__device__ __forceinline__ float fast_tanh(float x) {
    float e = __expf(2.0f * x);
    return 1.0f - 2.0f * fast_rcp(e + 1.0f);
}
__device__ __forceinline__ float fast_sigmoid(float x) {
    return fast_rcp(1.0f + __expf(-x));
}

// load 8 consecutive fp32 and round to bf16x8 (MFMA operand)
__device__ __forceinline__ bf16x8 cvt8(const float* __restrict__ p) {
    f32x4 a = *(const f32x4*)p;
    f32x4 b = *(const f32x4*)(p + 4);
    bf16x8 r;
    r[0] = (bf16)a[0]; r[1] = (bf16)a[1]; r[2] = (bf16)a[2]; r[3] = (bf16)a[3];
    r[4] = (bf16)b[0]; r[5] = (bf16)b[1]; r[6] = (bf16)b[2]; r[7] = (bf16)b[3];
    return r;
}
__device__ __forceinline__ bf16x8 cvt8v(f32x4 a, f32x4 b) {
    bf16x8 r;
    r[0] = (bf16)a[0]; r[1] = (bf16)a[1]; r[2] = (bf16)a[2]; r[3] = (bf16)a[3];
    r[4] = (bf16)b[0]; r[5] = (bf16)b[1]; r[6] = (bf16)b[2]; r[7] = (bf16)b[3];
    return r;
}

// ---- DPP 16-lane (same q-row) all-reduce sum on the VALU pipe ----
// row_ror:1/2/4/8 accumulation: after 4 steps every lane of each 16-lane
// DPP row holds the row sum. Replaces ds_bpermute-based __shfl_xor.
template <int CTRL>
__device__ __forceinline__ float dpp_add(float v) {
    int t = __builtin_amdgcn_update_dpp(0, __float_as_int(v), CTRL, 0xF, 0xF, false);
    return v + __int_as_float(t);
}
__device__ __forceinline__ float sum16(float v) {
    v = dpp_add<0x121>(v);  // row_ror:1
    v = dpp_add<0x122>(v);  // row_ror:2
    v = dpp_add<0x124>(v);  // row_ror:4
    v = dpp_add<0x128>(v);  // row_ror:8
    return v;
}

// ws layout (bytes):
//   [0,    8192)  Wf  bf16[64][64]  = W_mlp[:,0:64] @ W_init   (fused e-path weight)
//   [8192, 8320)  waf bf16[64]      = w_alpha[0:64] @ W_init
//   [8320, 8576)  bMf f32[64]       = b_mlp + W_mlp[:,0:64] @ b_init
//   [8576, 8580)  bAf f32[1]        = b_alpha + w_alpha[0:64] . b_init
//   [16384, ...)  node_fts cache in bf16 [N][64]   (if ws_size permits)
#define WS_WAF  8192
#define WS_BMF  8320
#define WS_BAF  8576
#define WS_NODE 16384

__global__ void prep_kernel(const float* __restrict__ W_init,
                            const float* __restrict__ b_init,
                            const float* __restrict__ W_mlp,
                            const float* __restrict__ b_mlp,
                            const float* __restrict__ W_alpha,
                            const float* __restrict__ b_alpha,
                            const float* __restrict__ node_fts,
                            char* __restrict__ ws,
                            int nchunks)
{
    const int idx = blockIdx.x * 256 + threadIdx.x;
    if (blockIdx.x < 17) {
        bf16*  Wf  = (bf16*)ws;
        bf16*  waf = (bf16*)(ws + WS_WAF);
        float* bMf = (float*)(ws + WS_BMF);
        float* bAf = (float*)(ws + WS_BAF);
        if (idx < 4096) {
            const int o = idx >> 6, k = idx & 63;
            float acc = 0.f;
            for (int j = 0; j < 64; ++j)
                acc += W_mlp[o * 192 + j] * W_init[j * 64 + k];
            Wf[o * 64 + k] = (bf16)acc;
        } else if (idx < 4160) {
            const int o = idx - 4096;
            float acc = b_mlp[o];
            for (int j = 0; j < 64; ++j)
                acc += W_mlp[o * 192 + j] * b_init[j];
            bMf[o] = acc;
        } else if (idx < 4224) {
            const int k = idx - 4160;
            float acc = 0.f;
            for (int j = 0; j < 64; ++j)
                acc += W_alpha[j] * W_init[j * 64 + k];
            waf[k] = (bf16)acc;
        } else if (idx == 4224) {
            float acc = b_alpha[0];
            for (int j = 0; j < 64; ++j)
                acc += W_alpha[j] * b_init[j];
            bAf[0] = acc;
        }
    } else {
        // node feature cache: fp32 -> bf16, 8 floats per thread
        const int i = idx - 17 * 256;
        if (i < nchunks) {
            bf16* nc = (bf16*)(ws + WS_NODE);
            f32x4 a = *(const f32x4*)(node_fts + (size_t)i * 8);
            f32x4 b = *(const f32x4*)(node_fts + (size_t)i * 8 + 4);
            *(bf16x8*)(nc + (size_t)i * 8) = cvt8v(a, b);
        }
    }
}

// issue all global loads for one pipeline stage (sp = stage parity 0/1)
#define ISSUE_STAGE(sp, e0s, hs, ts)                                          \
    {                                                                         \
        const float* ep_ = edge_fts + ((size_t)(e0s) + n) * 64;               \
        ef[sp][0] = *(const f32x4*)(ep_ + q * 8);                             \
        ef[sp][1] = *(const f32x4*)(ep_ + q * 8 + 4);                         \
        ef[sp][2] = *(const f32x4*)(ep_ + 32 + q * 8);                        \
        ef[sp][3] = *(const f32x4*)(ep_ + 32 + q * 8 + 4);                    \
        if constexpr (NB) {                                                   \
            const bf16* hp_ = nc + (size_t)(hs) * 64;                         \
            const bf16* tp_ = nc + (size_t)(ts) * 64;                         \
            nhB[sp][0] = *(const bf16x8*)(hp_ + q * 8);                       \
            nhB[sp][1] = *(const bf16x8*)(hp_ + 32 + q * 8);                  \
            ntB[sp][0] = *(const bf16x8*)(tp_ + q * 8);                       \
            ntB[sp][1] = *(const bf16x8*)(tp_ + 32 + q * 8);                  \
        } else {                                                              \
            const float* hp_ = node_fts + (size_t)(hs) * 64;                  \
            const float* tp_ = node_fts + (size_t)(ts) * 64;                  \
            nhF[sp][0] = *(const f32x4*)(hp_ + q * 8);                        \
            nhF[sp][1] = *(const f32x4*)(hp_ + q * 8 + 4);                    \
            nhF[sp][2] = *(const f32x4*)(hp_ + 32 + q * 8);                   \
            nhF[sp][3] = *(const f32x4*)(hp_ + 32 + q * 8 + 4);               \
            ntF[sp][0] = *(const f32x4*)(tp_ + q * 8);                        \
            ntF[sp][1] = *(const f32x4*)(tp_ + q * 8 + 4);                    \
            ntF[sp][2] = *(const f32x4*)(tp_ + 32 + q * 8);                   \
            ntF[sp][3] = *(const f32x4*)(tp_ + 32 + q * 8 + 4);               \
        }                                                                     \
    }

// One wave = 16 edges. 1-deep software pipeline over the grid-stride loop:
// while computing group g (stage p), loads for group g+stride (stage p^1)
// and indices for g+2*stride are in flight.
template <bool NB>
__global__ __launch_bounds__(256, 3)
void edge_update_kernel(const float* __restrict__ node_fts,
                        const float* __restrict__ edge_fts,
                        const int*   __restrict__ edges,
                        const float* __restrict__ W_init,
                        const float* __restrict__ b_init,
                        const float* __restrict__ W_mlp,
                        const float* __restrict__ W_alpha,
                        const char*  __restrict__ ws,
                        float* __restrict__ out,
                        int E)
{
    // cols 0..63 = Wf (fused e-path), 64..191 = W_mlp head/tail part,
    // 192..255 = W_init (B-frags for the residual GEMM). 264 = 256 + 8 pad.
    __shared__ bf16 sW2[64][264];
    __shared__ bf16 sWa[224];

    const int tid  = threadIdx.x;
    const int lane = tid & 63;
    const int wv   = tid >> 6;
    const int n    = lane & 15;   // MFMA col n / A-row m
    const int q    = lane >> 4;   // quad

    const bf16*  Wf  = (const bf16*)ws;
    const bf16*  waf = (const bf16*)(ws + WS_WAF);
    const float* bMf = (const float*)(ws + WS_BMF);
    const float* bAf = (const float*)(ws + WS_BAF);
    const bf16*  nc  = (const bf16*)(ws + WS_NODE);

    // ---- stage fused W2 + W_init + wa into LDS as bf16 ----
    for (int c = tid; c < 64 * 33; c += 256) {
        const int r = c / 33;
        const int o = (c - r * 33) * 8;
        if (o < 64)       *(bf16x8*)(&sW2[r][o]) = *(const bf16x8*)(Wf + r * 64 + o);
        else if (o < 192) *(bf16x8*)(&sW2[r][o]) = cvt8(W_mlp + r * 192 + o);
        else if (o < 256) *(bf16x8*)(&sW2[r][o]) = cvt8(W_init + r * 64 + (o - 192));
        // o == 256 is padding, never read
    }
    if (tid < 24) {
        const int o = tid * 8;
        if (o < 64) *(bf16x8*)(&sWa[o]) = *(const bf16x8*)(waf + o);
        else        *(bf16x8*)(&sWa[o]) = cvt8(W_alpha + o);
    }
    __syncthreads();

    float bI[4], bM[4];
    UNROLL
    for (int t = 0; t < 4; ++t) {
        bI[t] = b_init[t * 16 + n];
        bM[t] = bMf[t * 16 + n];
    }
    const float bA = bAf[0];

    const int ngroups = E >> 4;
    const int stride  = gridDim.x * 4;
    int gc = blockIdx.x * 4 + wv;
    if (gc >= ngroups) return;

    // pipeline stage registers
    f32x4  ef[2][4];
    bf16x8 nhB[2][2], ntB[2][2];   // bf16 node-cache path
    f32x4  nhF[2][4], ntF[2][4];   // fp32 fallback path

    // ---- prologue: stage 0 loads for gc; idx prefetch for gc+stride ----
    {
        const int e0 = gc << 4;
        const int hc = edges[e0 + n];
        const int tc = edges[E + e0 + n];
        ISSUE_STAGE(0, e0, hc, tc);
    }
    int gn = gc + stride, hn = 0, tn = 0;
    if (gn < ngroups) {
        const int e0n = gn << 4;
        hn = edges[e0n + n];
        tn = edges[E + e0n + n];
    } else {
        gn = gc;  // no next
    }

    for (;;) {
        UNROLL
        for (int p = 0; p < 2; ++p) {
            const int np = p ^ 1;
            const bool haveNext = (gn != gc);
            int g2 = gn;
            if (haveNext) {
                // issue next group's loads (in flight under this group's compute)
                ISSUE_STAGE(np, gn << 4, hn, tn);
                g2 = gn + stride;
                if (g2 < ngroups) {
                    const int e2 = g2 << 4;
                    hn = edges[e2 + n];
                    tn = edges[E + e2 + n];
                } else {
                    g2 = gn;
                }
            }

            // ---- compute current group gc from stage p ----
            const int e0c = gc << 4;
            bf16x8 A[6];
            A[0] = cvt8v(ef[p][0], ef[p][1]);
            A[1] = cvt8v(ef[p][2], ef[p][3]);
            if constexpr (NB) {
                A[2] = nhB[p][0]; A[3] = nhB[p][1];
                A[4] = ntB[p][0]; A[5] = ntB[p][1];
            } else {
                A[2] = cvt8v(nhF[p][0], nhF[p][1]); A[3] = cvt8v(nhF[p][2], nhF[p][3]);
                A[4] = cvt8v(ntF[p][0], ntF[p][1]); A[5] = cvt8v(ntF[p][2], ntF[p][3]);
            }

            // ---- GEMM-R: e (residual) in C-layout, B = W_init from LDS ----
            f32x4 accE[4] = { f32x4{0,0,0,0}, f32x4{0,0,0,0}, f32x4{0,0,0,0}, f32x4{0,0,0,0} };
            UNROLL
            for (int kk = 0; kk < 2; ++kk)
                UNROLL
                for (int t = 0; t < 4; ++t)
                    accE[t] = MFMA16(A[kk],
                                     *(const bf16x8*)(&sW2[t * 16 + n][192 + kk * 32 + q * 8]),
                                     accE[t]);

            // ---- GEMM2: K=192, 4 N-tiles + broadcast alpha column ----
            f32x4 accP[4] = { f32x4{0,0,0,0}, f32x4{0,0,0,0}, f32x4{0,0,0,0}, f32x4{0,0,0,0} };
            f32x4 accA = f32x4{0,0,0,0};
            UNROLL
            for (int kk = 0; kk < 6; ++kk) {
                accA = MFMA16(A[kk], *(const bf16x8*)(&sWa[kk * 32 + q * 8]), accA);
                UNROLL
                for (int t = 0; t < 4; ++t)
                    accP[t] = MFMA16(A[kk],
                                     *(const bf16x8*)(&sW2[t * 16 + n][kk * 32 + q * 8]),
                                     accP[t]);
            }

            // ---- epilogue: lane holds rows q*4+r, cols t*16+n ----
            float eF[4][4], pv[4][4], alpha[4];
            UNROLL
            for (int t = 0; t < 4; ++t)
                UNROLL
                for (int r = 0; r < 4; ++r) eF[t][r] = accE[t][r] + bI[t];
            UNROLL
            for (int r = 0; r < 4; ++r) alpha[r] = fast_sigmoid(accA[r] + bA);
            UNROLL
            for (int t = 0; t < 4; ++t)
                UNROLL
                for (int r = 0; r < 4; ++r) pv[t][r] = fast_tanh(accP[t][r] + bM[t]);

            // LN1 over 64 cols: per-lane partials, DPP row-ror all-reduce over 16 n-lanes
            float s1[4], s2[4];
            UNROLL
            for (int r = 0; r < 4; ++r) {
                s1[r] = pv[0][r] + pv[1][r] + pv[2][r] + pv[3][r];
                s2[r] = pv[0][r]*pv[0][r] + pv[1][r]*pv[1][r] + pv[2][r]*pv[2][r] + pv[3][r]*pv[3][r];
            }
            UNROLL
            for (int r = 0; r < 4; ++r) { s1[r] = sum16(s1[r]); s2[r] = sum16(s2[r]); }

            float o2[4][4];
            UNROLL
            for (int r = 0; r < 4; ++r) {
                const float mean = s1[r] * 0.015625f;
                const float var  = fmaxf(s2[r] * 0.015625f - mean * mean, 0.0f);
                const float rs   = fast_rsq(var + 1e-5f);
                UNROLL
                for (int t = 0; t < 4; ++t)
                    o2[t][r] = eF[t][r] + (pv[t][r] - mean) * rs * alpha[r];
            }

            // LN2
            UNROLL
            for (int r = 0; r < 4; ++r) {
                s1[r] = o2[0][r] + o2[1][r] + o2[2][r] + o2[3][r];
                s2[r] = o2[0][r]*o2[0][r] + o2[1][r]*o2[1][r] + o2[2][r]*o2[2][r] + o2[3][r]*o2[3][r];
            }
            UNROLL
            for (int r = 0; r < 4; ++r) { s1[r] = sum16(s1[r]); s2[r] = sum16(s2[r]); }

            UNROLL
            for (int r = 0; r < 4; ++r) {
                const float mean = s1[r] * 0.015625f;
                const float var  = fmaxf(s2[r] * 0.015625f - mean * mean, 0.0f);
                const float rs   = fast_rsq(var + 1e-5f);
                UNROLL
                for (int t = 0; t < 4; ++t)
                    out[((size_t)e0c + q * 4 + r) * 64 + t * 16 + n] = (o2[t][r] - mean) * rs;
            }

            if (!haveNext) return;
            gc = gn;
            gn = g2;
        }
    }
}

extern "C" void kernel_launch(void* const* d_in, const int* in_sizes, int n_in,
                              void* d_out, int out_size, void* d_ws, size_t ws_size,
                              hipStream_t stream) {
    const float* node_fts = (const float*)d_in[0];
    const float* edge_fts = (const float*)d_in[1];
    const int*   edges    = (const int*)d_in[2];
    const float* W_init   = (const float*)d_in[3];
    const float* b_init   = (const float*)d_in[4];
    const float* W_mlp    = (const float*)d_in[5];
    const float* b_mlp    = (const float*)d_in[6];
    const float* W_alpha  = (const float*)d_in[7];
    const float* b_alpha  = (const float*)d_in[8];
    float* out = (float*)d_out;
    char*  ws  = (char*)d_ws;

    const int E = in_sizes[2] / 2;       // edges is [2, E]
    const int N = in_sizes[0] / 64;      // node_fts is [N, 64]

    const size_t need = (size_t)WS_NODE + (size_t)N * 64 * 2;
    const bool   nb   = ws_size >= need;
    const int    nchunks = N * 8;        // 8 floats per chunk

    const int prep_blocks = nb ? (17 + (nchunks + 255) / 256) : 17;
    hipLaunchKernelGGL(prep_kernel, dim3(prep_blocks), dim3(256), 0, stream,
                       W_init, b_init, W_mlp, b_mlp, W_alpha, b_alpha,
                       node_fts, ws, nb ? nchunks : 0);

    if (nb) {
        hipLaunchKernelGGL((edge_update_kernel<true>), dim3(2048), dim3(256), 0, stream,
                           node_fts, edge_fts, edges, W_init, b_init,
                           W_mlp, W_alpha, ws, out, E);
    } else {
        hipLaunchKernelGGL((edge_update_kernel<false>), dim3(2048), dim3(256), 0, stream,
                           node_fts, edge_fts, edges, W_init, b_init,
                           W_mlp, W_alpha, ws, out, E);
    }
}